// Round 1
// baseline (97.105 us; speedup 1.0000x reference)
//
#include <hip/hip_runtime.h>
#include <hip/hip_bf16.h>
#include <cstdint>

#define IN_DIM 512
#define KEY_DIM 512
#define OUT_DIM 512
#define FLT 32
#define STRIDEV 4
#define BATCH 8
#define TT 2048
#define TOUT 505                         // (2048-32)/4+1
#define MROWS (BATCH * TT)               // 16384
#define NCOLS (KEY_DIM + KEY_DIM + OUT_DIM)  // 1536
#define KDIM IN_DIM                      // 512

#define BM 128
#define BN 128
#define BK 64

typedef float f32x4 __attribute__((ext_vector_type(4)));
typedef __bf16 bf16x8 __attribute__((ext_vector_type(8)));

static __device__ __forceinline__ ushort f2bf(float f) {
  uint32_t u = __float_as_uint(f);
  uint32_t r = (u + 0x7fffu + ((u >> 16) & 1u)) >> 16;
  return (ushort)r;
}
static __device__ __forceinline__ float bf2f(ushort h) {
  return __uint_as_float(((uint32_t)h) << 16);
}

// ---------------- prep: cast x to bf16 (vectorized) ----------------
__global__ void prep_x_kernel(const float* __restrict__ x, ushort* __restrict__ xb) {
  int i = blockIdx.x * blockDim.x + threadIdx.x;  // handles 4 elements
  float4 v = reinterpret_cast<const float4*>(x)[i];
  ushort4 o;
  o.x = f2bf(v.x); o.y = f2bf(v.y); o.z = f2bf(v.z); o.w = f2bf(v.w);
  reinterpret_cast<ushort4*>(xb)[i] = o;
}

// ---------------- prep: W -> Wt[N][K] bf16 (B^T layout), bias fuse ----------
__global__ void prep_w_kernel(const float* __restrict__ Wq, const float* __restrict__ Wk,
                              const float* __restrict__ Wv, const float* __restrict__ bq,
                              const float* __restrict__ bk, const float* __restrict__ bv,
                              ushort* __restrict__ wt, float* __restrict__ bias) {
  int e = blockIdx.x * 256 + threadIdx.x;
  if (e < NCOLS * KDIM) {
    int n = e >> 9;       // row of Wt (output column)
    int k = e & 511;
    const float* W = (n < 512) ? Wq : (n < 1024) ? Wk : Wv;
    int nn = n & 511;
    wt[e] = f2bf(W[k * 512 + nn]);
  } else {
    int n = e - NCOLS * KDIM;
    if (n < NCOLS) {
      const float* bsrc = (n < 512) ? bq : (n < 1024) ? bk : bv;
      bias[n] = bsrc[n & 511];
    }
  }
}

// ---------------- GEMM: qkv = x @ [Wq|Wk|Wv] + bias (bf16 MFMA) ----------------
__global__ __launch_bounds__(256, 2) void gemm_qkv_kernel(
    const ushort* __restrict__ xb,   // [MROWS][KDIM] bf16
    const ushort* __restrict__ wt,   // [NCOLS][KDIM] bf16 (B^T)
    const float* __restrict__ bias,  // [NCOLS]
    ushort* __restrict__ qkv)        // [MROWS][NCOLS] bf16
{
  __shared__ ushort As[BM * BK];
  __shared__ ushort Bs[BN * BK];

  const int tid = threadIdx.x;
  const int lane = tid & 63;
  const int wv = tid >> 6;          // 0..3
  const int nb = NCOLS / BN;        // 12
  const int bm = blockIdx.x / nb;
  const int bn = blockIdx.x % nb;
  const int m0 = bm * BM;
  const int n0 = bn * BN;

  const int wr = wv >> 1;           // wave row 0..1
  const int wc = wv & 1;            // wave col 0..1
  const int fr = lane & 15;
  const int fq = lane >> 4;

  f32x4 acc[4][4];
  #pragma unroll
  for (int i = 0; i < 4; ++i)
    #pragma unroll
    for (int j = 0; j < 4; ++j) acc[i][j] = (f32x4){0.f, 0.f, 0.f, 0.f};

  for (int k0 = 0; k0 < KDIM; k0 += BK) {
    __syncthreads();
    #pragma unroll
    for (int i = 0; i < 4; ++i) {
      int boff = i * 4096 + wv * 1024 + lane * 16;  // byte offset into tile
      int eoff = boff >> 1;
      int row = eoff >> 6;          // / BK
      int col = eoff & (BK - 1);
      const ushort* ga = xb + (size_t)(m0 + row) * KDIM + k0 + col;
      __builtin_amdgcn_global_load_lds(
          (const __attribute__((address_space(1))) unsigned int*)ga,
          (__attribute__((address_space(3))) unsigned int*)((char*)As + i * 4096 + wv * 1024),
          16, 0, 0);
      const ushort* gb = wt + (size_t)(n0 + row) * KDIM + k0 + col;
      __builtin_amdgcn_global_load_lds(
          (const __attribute__((address_space(1))) unsigned int*)gb,
          (__attribute__((address_space(3))) unsigned int*)((char*)Bs + i * 4096 + wv * 1024),
          16, 0, 0);
    }
    __syncthreads();

    #pragma unroll
    for (int ks = 0; ks < 2; ++ks) {
      bf16x8 af[4], bf[4];
      #pragma unroll
      for (int i = 0; i < 4; ++i) {
        af[i] = *reinterpret_cast<const bf16x8*>(&As[(wr * 64 + i * 16 + fr) * BK + ks * 32 + fq * 8]);
        bf[i] = *reinterpret_cast<const bf16x8*>(&Bs[(wc * 64 + i * 16 + fr) * BK + ks * 32 + fq * 8]);
      }
      #pragma unroll
      for (int i = 0; i < 4; ++i)
        #pragma unroll
        for (int j = 0; j < 4; ++j)
          acc[i][j] = __builtin_amdgcn_mfma_f32_16x16x32_bf16(af[i], bf[j], acc[i][j], 0, 0, 0);
    }
  }

  // epilogue: bias + bf16 store.  D: row=(lane>>4)*4+r, col=lane&15  [verified mapping]
  #pragma unroll
  for (int j = 0; j < 4; ++j) {
    int col = n0 + wc * 64 + j * 16 + fr;
    float bvl = bias[col];
    #pragma unroll
    for (int i = 0; i < 4; ++i) {
      int rowb = m0 + wr * 64 + i * 16 + fq * 4;
      #pragma unroll
      for (int r = 0; r < 4; ++r) {
        qkv[(size_t)(rowb + r) * NCOLS + col] = f2bf(acc[i][j][r] + bvl);
      }
    }
  }
}

// ---------------- windowed attention ----------------
__global__ __launch_bounds__(256) void attn_kernel(
    const ushort* __restrict__ qkv,  // [MROWS][NCOLS] bf16: [q|k|v]
    float* __restrict__ out)         // [B][TOUT][OUT_DIM] fp32
{
  __shared__ float q_lds[KEY_DIM];
  __shared__ float s_lds[FLT];
  __shared__ float p_lds[FLT];

  const int blk = blockIdx.x;
  const int b = blk / TOUT;
  const int t = blk - b * TOUT;
  const size_t base_row = (size_t)b * TT + (size_t)t * STRIDEV;
  const int tid = threadIdx.x;
  const int lane = tid & 63;
  const int wv = tid >> 6;

  // center q row -> LDS (fp32)
  {
    const ushort* qrow = qkv + (base_row + FLT / 2) * NCOLS;
    uint v = *reinterpret_cast<const uint*>(qrow + tid * 2);
    q_lds[tid * 2]     = bf2f((ushort)(v & 0xffffu));
    q_lds[tid * 2 + 1] = bf2f((ushort)(v >> 16));
  }
  __syncthreads();

  // phase 1: 32 scores; 8 lanes per score, 64 dims per lane
  const int fl = lane >> 3;
  const int f = wv * 8 + fl;
  const int sub = lane & 7;
  const ushort* krow = qkv + (base_row + f) * NCOLS + KEY_DIM;
  float acc = 0.f;
  #pragma unroll
  for (int j = 0; j < 8; ++j) {
    int d = (j * 8 + sub) * 8;
    uint4 kv4 = *reinterpret_cast<const uint4*>(krow + d);
    const ushort* ks = reinterpret_cast<const ushort*>(&kv4);
    #pragma unroll
    for (int e = 0; e < 8; ++e) acc += q_lds[d + e] * bf2f(ks[e]);
  }
  acc += __shfl_xor(acc, 1);
  acc += __shfl_xor(acc, 2);
  acc += __shfl_xor(acc, 4);
  if (sub == 0) s_lds[f] = acc * 0.04419417382415922f;  // 1/sqrt(512)
  __syncthreads();

  // phase 2: softmax over 32 (redundant max, 32 threads do exp)
  float m = -1e30f;
  #pragma unroll
  for (int i = 0; i < FLT; ++i) m = fmaxf(m, s_lds[i]);
  if (tid < FLT) p_lds[tid] = __expf(s_lds[tid] - m);
  __syncthreads();
  float sum = 0.f;
  #pragma unroll
  for (int i = 0; i < FLT; ++i) sum += p_lds[i];
  const float inv = 1.f / sum;

  // phase 3: out[d] = sum_f w_f * v[f][d]; 2 dims/thread
  const int d = tid * 2;
  float o0 = 0.f, o1 = 0.f;
  const ushort* vbase = qkv + base_row * NCOLS + 2 * KEY_DIM + d;
  #pragma unroll
  for (int ff = 0; ff < FLT; ++ff) {
    uint vv = *reinterpret_cast<const uint*>(vbase + (size_t)ff * NCOLS);
    float w = p_lds[ff] * inv;
    o0 += w * bf2f((ushort)(vv & 0xffffu));
    o1 += w * bf2f((ushort)(vv >> 16));
  }
  float2* op = reinterpret_cast<float2*>(out + ((size_t)b * TOUT + t) * OUT_DIM + d);
  *op = make_float2(o0, o1);
}

// ---------------- launch ----------------
extern "C" void kernel_launch(void* const* d_in, const int* in_sizes, int n_in,
                              void* d_out, int out_size, void* d_ws, size_t ws_size,
                              hipStream_t stream) {
  const float* x  = (const float*)d_in[0];
  const float* Wq = (const float*)d_in[1];
  const float* bq = (const float*)d_in[2];
  const float* Wk = (const float*)d_in[3];
  const float* bk = (const float*)d_in[4];
  const float* Wv = (const float*)d_in[5];
  const float* bv = (const float*)d_in[6];
  float* out = (float*)d_out;

  char* ws = (char*)d_ws;
  // ws layout: xb 16777216 | wt 1572864 | bias 8192 | qkv 50331648  = 68,689,920 B
  ushort* xb  = (ushort*)ws;
  ushort* wt  = (ushort*)(ws + 16777216);
  float*  bias = (float*)(ws + 16777216 + 1572864);
  ushort* qkv = (ushort*)(ws + 16777216 + 1572864 + 8192);

  hipLaunchKernelGGL(prep_x_kernel, dim3(MROWS * KDIM / 4 / 256), dim3(256), 0, stream, x, xb);
  hipLaunchKernelGGL(prep_w_kernel, dim3((NCOLS * KDIM + NCOLS + 255) / 256), dim3(256), 0, stream,
                     Wq, Wk, Wv, bq, bk, bv, wt, bias);
  hipLaunchKernelGGL(gemm_qkv_kernel, dim3((MROWS / BM) * (NCOLS / BN)), dim3(256), 0, stream,
                     xb, wt, bias, qkv);
  hipLaunchKernelGGL(attn_kernel, dim3(BATCH * TOUT), dim3(256), 0, stream, qkv, out);
}

// Round 2
// 77.369 us; speedup vs baseline: 1.2551x; 1.2551x over previous
//
#include <hip/hip_runtime.h>
#include <hip/hip_bf16.h>
#include <cstdint>

#define IN_DIM 512
#define KEY_DIM 512
#define OUT_DIM 512
#define FLT 32
#define STRIDEV 4
#define BATCH 8
#define TT 2048
#define TOUT 505                         // (2048-32)/4+1
#define MROWS (BATCH * TT)               // 16384
#define QROWS (BATCH * TOUT)             // 4040
#define KDIM IN_DIM                      // 512

#define BM 128
#define BN 128
#define BK 64

typedef float f32x4 __attribute__((ext_vector_type(4)));
typedef __bf16 bf16x8 __attribute__((ext_vector_type(8)));

static __device__ __forceinline__ ushort f2bf(float f) {
  uint32_t u = __float_as_uint(f);
  uint32_t r = (u + 0x7fffu + ((u >> 16) & 1u)) >> 16;
  return (ushort)r;
}
static __device__ __forceinline__ float bf2f(ushort h) {
  return __uint_as_float(((uint32_t)h) << 16);
}

// ---------------- prep: cast x to bf16 (vectorized) ----------------
__global__ void prep_x_kernel(const float* __restrict__ x, ushort* __restrict__ xb) {
  int i = blockIdx.x * blockDim.x + threadIdx.x;  // handles 4 elements
  float4 v = reinterpret_cast<const float4*>(x)[i];
  ushort4 o;
  o.x = f2bf(v.x); o.y = f2bf(v.y); o.z = f2bf(v.z); o.w = f2bf(v.w);
  reinterpret_cast<ushort4*>(xb)[i] = o;
}

// ---------------- prep: W -> Wt[N][K] bf16 (B^T layout), 16B writes ---------
__global__ void prep_w_kernel(const float* __restrict__ Wq, const float* __restrict__ Wk,
                              const float* __restrict__ Wv, const float* __restrict__ bq,
                              const float* __restrict__ bk, const float* __restrict__ bv,
                              ushort* __restrict__ wt, float* __restrict__ bias) {
  int idx = blockIdx.x * 256 + threadIdx.x;
  const int NG = 1536 * 512 / 8;  // 98304 groups of 8 k-elements
  if (idx < NG) {
    int n = idx >> 6;            // output row (q|k|v column), 0..1535
    int k0 = (idx & 63) * 8;
    const float* W = (n < 512) ? Wq : (n < 1024) ? Wk : Wv;
    int nn = n & 511;
    ushort v8[8];
    #pragma unroll
    for (int e = 0; e < 8; ++e) v8[e] = f2bf(W[(size_t)(k0 + e) * 512 + nn]);
    *reinterpret_cast<uint4*>(&wt[(size_t)n * 512 + k0]) =
        *reinterpret_cast<const uint4*>(v8);
  } else {
    int n = idx - NG;
    if (n < 1536) {
      const float* bsrc = (n < 512) ? bq : (n < 1024) ? bk : bv;
      bias[n] = bsrc[n & 511];
    }
  }
}

// ---------------- GEMM (bf16 MFMA, st-swizzled LDS, XCD-swizzled grid) ------
// out[M][NSTRIDE] = A @ Wt^T + bias.  A rows linear (kv) or gathered centers (q).
template <int NBN, int NSTRIDE, bool GATHER>
__global__ __launch_bounds__(256, 4) void gemm_kernel(
    const ushort* __restrict__ xb,   // [MROWS][KDIM] bf16
    const ushort* __restrict__ wt,   // [NSTRIDE][KDIM] bf16 (B^T)
    const float* __restrict__ bias,  // [NSTRIDE]
    ushort* __restrict__ outp)       // [M][NSTRIDE] bf16
{
  __shared__ ushort As[BM * BK];
  __shared__ ushort Bs[BN * BK];

  const int tid = threadIdx.x;
  const int lane = tid & 63;
  const int wv = tid >> 6;          // 0..3

  // bijective XCD swizzle (gridDim %8 == 0): XCD x owns a contiguous chunk
  const int per = gridDim.x >> 3;
  const int swz = (blockIdx.x & 7) * per + (blockIdx.x >> 3);
  const int bm = swz / NBN;
  const int bn = swz % NBN;
  const int m0 = bm * BM;
  const int n0 = bn * BN;

  const int wr = wv >> 1;
  const int wc = wv & 1;
  const int fr = lane & 15;
  const int fq = lane >> 4;

  f32x4 acc[4][4];
  #pragma unroll
  for (int i = 0; i < 4; ++i)
    #pragma unroll
    for (int j = 0; j < 4; ++j) acc[i][j] = (f32x4){0.f, 0.f, 0.f, 0.f};

  for (int k0 = 0; k0 < KDIM; k0 += BK) {
    __syncthreads();
    #pragma unroll
    for (int i = 0; i < 4; ++i) {
      int boff = i * 4096 + wv * 1024 + lane * 16;  // linear LDS byte offset
      int row = boff >> 7;                          // 128 B per tile row
      int colb = boff & 127;
      // inverse-swizzled SOURCE column (involution), LDS dest stays linear
      int scol = (colb ^ ((row & 7) << 4)) >> 1;    // element col in [0,BK)
      size_t arow;
      if (GATHER) {
        int r = m0 + row;
        if (r > QROWS - 1) r = QROWS - 1;           // clamp (dup load, no store)
        int bb = r / TOUT;
        int tt = r - bb * TOUT;
        arow = (size_t)bb * TT + (size_t)tt * STRIDEV + FLT / 2;
      } else {
        arow = (size_t)(m0 + row);
      }
      const ushort* ga = xb + arow * KDIM + k0 + scol;
      __builtin_amdgcn_global_load_lds(
          (const __attribute__((address_space(1))) unsigned int*)ga,
          (__attribute__((address_space(3))) unsigned int*)((char*)As + i * 4096 + wv * 1024),
          16, 0, 0);
      const ushort* gb = wt + (size_t)(n0 + row) * KDIM + k0 + scol;
      __builtin_amdgcn_global_load_lds(
          (const __attribute__((address_space(1))) unsigned int*)gb,
          (__attribute__((address_space(3))) unsigned int*)((char*)Bs + i * 4096 + wv * 1024),
          16, 0, 0);
    }
    __syncthreads();

    #pragma unroll
    for (int ks = 0; ks < 2; ++ks) {
      bf16x8 af[4], bff[4];
      #pragma unroll
      for (int i = 0; i < 4; ++i) {
        int ra = wr * 64 + i * 16 + fr;
        int ca = ks * 64 + fq * 16;                 // byte col
        af[i] = *reinterpret_cast<const bf16x8*>(
            (char*)As + ra * 128 + (ca ^ ((ra & 7) << 4)));
        int rb = wc * 64 + i * 16 + fr;
        bff[i] = *reinterpret_cast<const bf16x8*>(
            (char*)Bs + rb * 128 + (ca ^ ((rb & 7) << 4)));
      }
      #pragma unroll
      for (int i = 0; i < 4; ++i)
        #pragma unroll
        for (int j = 0; j < 4; ++j)
          acc[i][j] = __builtin_amdgcn_mfma_f32_16x16x32_bf16(af[i], bff[j], acc[i][j], 0, 0, 0);
    }
  }

  // epilogue: bias + bf16 store.  D: row=(lane>>4)*4+r, col=lane&15
  #pragma unroll
  for (int j = 0; j < 4; ++j) {
    int col = n0 + wc * 64 + j * 16 + fr;
    float bvl = bias[col];
    #pragma unroll
    for (int i = 0; i < 4; ++i) {
      int rowb = m0 + wr * 64 + i * 16 + fq * 4;
      #pragma unroll
      for (int r = 0; r < 4; ++r) {
        if (!GATHER || (rowb + r) < QROWS)
          outp[(size_t)(rowb + r) * NSTRIDE + col] = f2bf(acc[i][j][r] + bvl);
      }
    }
  }
}

// ---------------- windowed attention ----------------
__global__ __launch_bounds__(256) void attn_kernel(
    const ushort* __restrict__ kv,   // [MROWS][1024] bf16: [k|v]
    const ushort* __restrict__ qc,   // [QROWS][512] bf16 (center q rows)
    float* __restrict__ out)         // [B][TOUT][OUT_DIM] fp32
{
  __shared__ float q_lds[KEY_DIM];
  __shared__ float s_lds[FLT];
  __shared__ float p_lds[FLT];

  // XCD swizzle: 4040 = 8*505 -> batch b pinned to XCD (bid&7), t sequential
  const int bid = blockIdx.x;
  const int b = bid & 7;
  const int t = bid >> 3;
  const size_t base_row = (size_t)b * TT + (size_t)t * STRIDEV;
  const int tid = threadIdx.x;
  const int lane = tid & 63;
  const int wv = tid >> 6;

  // center q row -> LDS (fp32)
  {
    const ushort* qrow = qc + ((size_t)b * TOUT + t) * KEY_DIM;
    uint v = *reinterpret_cast<const uint*>(qrow + tid * 2);
    q_lds[tid * 2]     = bf2f((ushort)(v & 0xffffu));
    q_lds[tid * 2 + 1] = bf2f((ushort)(v >> 16));
  }
  __syncthreads();

  // phase 1: 32 scores; 8 lanes per score, 64 dims per lane
  const int fl = lane >> 3;
  const int f = wv * 8 + fl;
  const int sub = lane & 7;
  const ushort* krow = kv + (base_row + f) * 1024;
  float acc = 0.f;
  #pragma unroll
  for (int j = 0; j < 8; ++j) {
    int d = (j * 8 + sub) * 8;
    uint4 kv4 = *reinterpret_cast<const uint4*>(krow + d);
    const ushort* ks = reinterpret_cast<const ushort*>(&kv4);
    #pragma unroll
    for (int e = 0; e < 8; ++e) acc += q_lds[d + e] * bf2f(ks[e]);
  }
  acc += __shfl_xor(acc, 1);
  acc += __shfl_xor(acc, 2);
  acc += __shfl_xor(acc, 4);
  if (sub == 0) s_lds[f] = acc * 0.04419417382415922f;  // 1/sqrt(512)
  __syncthreads();

  // phase 2: softmax over 32
  float m = -1e30f;
  #pragma unroll
  for (int i = 0; i < FLT; ++i) m = fmaxf(m, s_lds[i]);
  if (tid < FLT) p_lds[tid] = __expf(s_lds[tid] - m);
  __syncthreads();
  float sum = 0.f;
  #pragma unroll
  for (int i = 0; i < FLT; ++i) sum += p_lds[i];
  const float inv = 1.f / sum;

  // phase 3: out[d] = sum_f w_f * v[f][d]; 2 dims/thread
  const int d = tid * 2;
  float o0 = 0.f, o1 = 0.f;
  const ushort* vbase = kv + base_row * 1024 + 512 + d;
  #pragma unroll
  for (int ff = 0; ff < FLT; ++ff) {
    uint vv = *reinterpret_cast<const uint*>(vbase + (size_t)ff * 1024);
    float w = p_lds[ff] * inv;
    o0 += w * bf2f((ushort)(vv & 0xffffu));
    o1 += w * bf2f((ushort)(vv >> 16));
  }
  float2* op = reinterpret_cast<float2*>(out + ((size_t)b * TOUT + t) * OUT_DIM + d);
  *op = make_float2(o0, o1);
}

// ---------------- launch ----------------
extern "C" void kernel_launch(void* const* d_in, const int* in_sizes, int n_in,
                              void* d_out, int out_size, void* d_ws, size_t ws_size,
                              hipStream_t stream) {
  const float* x  = (const float*)d_in[0];
  const float* Wq = (const float*)d_in[1];
  const float* bq = (const float*)d_in[2];
  const float* Wk = (const float*)d_in[3];
  const float* bk = (const float*)d_in[4];
  const float* Wv = (const float*)d_in[5];
  const float* bv = (const float*)d_in[6];
  float* out = (float*)d_out;

  char* ws = (char*)d_ws;
  // ws layout: xb 16MiB | wt 1.5MiB | bias 8KiB | kv 32MiB | qc ~4MiB
  ushort* xb   = (ushort*)ws;
  ushort* wt   = (ushort*)(ws + 16777216);
  float*  bias = (float*)(ws + 16777216 + 1572864);
  ushort* kv   = (ushort*)(ws + 16777216 + 1572864 + 8192);           // 18358272
  ushort* qc   = (ushort*)(ws + 18358272 + (size_t)MROWS * 1024 * 2); // 51912704

  hipLaunchKernelGGL(prep_x_kernel, dim3(MROWS * KDIM / 4 / 256), dim3(256), 0, stream, x, xb);
  hipLaunchKernelGGL(prep_w_kernel, dim3(390), dim3(256), 0, stream,
                     Wq, Wk, Wv, bq, bk, bv, wt, bias);
  // k,v GEMM: N=1024 (wt rows 512..1535), out stride 1024
  hipLaunchKernelGGL((gemm_kernel<8, 1024, false>), dim3((MROWS / BM) * 8), dim3(256), 0, stream,
                     xb, wt + (size_t)512 * 512, bias + 512, kv);
  // q GEMM: gathered center rows, N=512, out [4040][512]
  hipLaunchKernelGGL((gemm_kernel<4, 512, true>), dim3(32 * 4), dim3(256), 0, stream,
                     xb, wt, bias, qc);
  hipLaunchKernelGGL(attn_kernel, dim3(BATCH * TOUT), dim3(256), 0, stream, kv, qc, out);
}